// Round 7
// baseline (398.064 us; speedup 1.0000x reference)
//
#include <hip/hip_runtime.h>
#include <hip/hip_fp16.h>
#include <math.h>

#define HW 65536  // 256*256

typedef float v2f __attribute__((ext_vector_type(2), aligned(4)));
typedef _Float16 h2 __attribute__((ext_vector_type(2)));

// ---------------- K1: in_conv 1x1, 64 -> 16 (float2/thread) ----------------
__global__ __launch_bounds__(256) void k_inconv(const float* __restrict__ cen,
                                                const float* __restrict__ w,
                                                const float* __restrict__ bias,
                                                float* __restrict__ x) {
    __shared__ float sw[1024];
    __shared__ float sb[16];
    int tid = threadIdx.x;
    for (int i = tid; i < 1024; i += 256) sw[i] = w[i];
    if (tid < 16) sb[tid] = bias[tid];
    __syncthreads();

    long t  = (long)blockIdx.x * 256 + tid;   // pair index
    long p0 = t * 2;
    int  b  = (int)(p0 >> 16);
    int  hw = (int)(p0 & 65535);

    const float2* src = (const float2*)(cen + ((long)b * 64) * HW + hw);
    float2 acc[16];
#pragma unroll
    for (int o = 0; o < 16; o++) { float bv = sb[o]; acc[o] = make_float2(bv, bv); }

#pragma unroll 8
    for (int i = 0; i < 64; i++) {
        float2 v = src[(long)i * (HW / 2)];
#pragma unroll
        for (int o = 0; o < 16; o++) {
            float wv = sw[o * 64 + i];
            acc[o].x = fmaf(v.x, wv, acc[o].x);
            acc[o].y = fmaf(v.y, wv, acc[o].y);
        }
    }
    float2* dst = (float2*)(x + ((long)b * 16) * HW + hw);
#pragma unroll
    for (int o = 0; o < 16; o++) dst[(long)o * (HW / 2)] = acc[o];
}

// ---------------- K2: fused branch machinery ----------------
// fp16 packed sort (v_pk_min/max_f16), 2 pixels per lane
#define CEH(a, b) { h2 _t = __builtin_elementwise_min(a, b); \
                    b = __builtin_elementwise_max(a, b); a = _t; }

__device__ __forceinline__ void sort8_h2(h2* v) {
    CEH(v[0], v[1]); CEH(v[2], v[3]); CEH(v[4], v[5]); CEH(v[6], v[7]);
    CEH(v[0], v[2]); CEH(v[1], v[3]); CEH(v[4], v[6]); CEH(v[5], v[7]);
    CEH(v[1], v[2]); CEH(v[5], v[6]); CEH(v[0], v[4]); CEH(v[3], v[7]);
    CEH(v[1], v[5]); CEH(v[2], v[6]);
    CEH(v[1], v[4]); CEH(v[3], v[6]);
    CEH(v[2], v[4]); CEH(v[3], v[5]);
    CEH(v[3], v[4]);
}
__device__ __forceinline__ void sort4_h2(h2* v) {
    CEH(v[0], v[1]); CEH(v[2], v[3]); CEH(v[0], v[2]); CEH(v[1], v[3]); CEH(v[1], v[2]);
}

// ODD strides: row stride mod 32 is odd -> alternating bank parity -> no
// systematic same-parity pileup (the even strides 56/48 caused a 2x conflict
// on every LDS access: all 64 lanes on 16 banks).
#define LXS 53              // lx stride
#define SS  47              // lxs stride; s odd => all pair offsets even => 8B aligned

__global__ __launch_bounds__(512, 4) void k_main(
    const float* __restrict__ x,
    const float* __restrict__ dw_w1, const float* __restrict__ dw_b1,
    const float* __restrict__ dw_w3, const float* __restrict__ dw_b3,
    const float* __restrict__ dw_w5, const float* __restrict__ dw_b5,
    const float* __restrict__ dw_w7, const float* __restrict__ dw_b7,
    const float* __restrict__ l1w, const float* __restrict__ l1b,
    const float* __restrict__ l2w, const float* __restrict__ l2b,
    const float* __restrict__ bw,  const float* __restrict__ bns,
    const float* __restrict__ bnb, __half* __restrict__ y16) {

    const int plane = blockIdx.y;          // b*16 + c
    const int c     = plane & 15;
    const int ty0   = (blockIdx.x >> 3) * 32;
    const int tx0   = (blockIdx.x & 7) * 32;
    const int tid   = threadIdx.x;

    __shared__ float lx[52 * LXS];         // x tile + halo 10
    __shared__ float lxs[4][46 * SS];      // dw outputs (zeroed outside image), halo 7

    const float* xp = x + (long)plane * HW;

    // ---- stage x tile (52x52, origin (ty0-10, tx0-10)), zero outside ----
    for (int i = tid; i < 52 * 52; i += 512) {
        int r  = i / 52;
        int cc = i - r * 52;
        int gy = ty0 - 10 + r, gx = tx0 - 10 + cc;
        float v = 0.f;
        if ((unsigned)gy < 256u && (unsigned)gx < 256u) v = xp[gy * 256 + gx];
        lx[r * LXS + cc] = v;
    }
    __syncthreads();

    // ---- depthwise convs into lxs over 46x46 (tile + halo 7), scalar FMA ----
    const float* W7 = dw_w7 + c * 49;
    const float* W5 = dw_w5 + c * 25;
    const float* W3 = dw_w3 + c * 9;
    const float  W1 = dw_w1[c];
    const float  B1 = dw_b1[c], B3 = dw_b3[c], B5 = dw_b5[c], B7 = dw_b7[c];

    for (int u = tid; u < 46 * 23; u += 512) {   // 46 rows x 23 groups of 2 cols
        int row = u / 23;
        int pc0 = (u - row * 23) * 2;
        float c7[2] = {0, 0}, c5[2] = {0, 0}, c3[2] = {0, 0}, c1[2] = {0, 0};
#pragma unroll
        for (int a = 0; a < 7; a++) {
            const float* rp = &lx[(row + a) * LXS + pc0];
            float v[9];
#pragma unroll
            for (int j = 0; j < 9; j++) v[j] = rp[j];
#pragma unroll
            for (int j = 0; j < 2; j++) {
#pragma unroll
                for (int bb = 0; bb < 7; bb++)
                    c7[j] = fmaf(v[j + bb], W7[a * 7 + bb], c7[j]);
                if (a >= 1 && a <= 5) {
#pragma unroll
                    for (int bb = 0; bb < 5; bb++)
                        c5[j] = fmaf(v[j + 1 + bb], W5[(a - 1) * 5 + bb], c5[j]);
                }
                if (a >= 2 && a <= 4) {
#pragma unroll
                    for (int bb = 0; bb < 3; bb++)
                        c3[j] = fmaf(v[j + 2 + bb], W3[(a - 2) * 3 + bb], c3[j]);
                }
                if (a == 3) c1[j] = v[j + 3] * W1;
            }
        }
        int gy  = ty0 - 7 + row;
        int gx0 = tx0 - 7 + pc0;
        bool rin = ((unsigned)gy < 256u);
        bool in0 = rin && ((unsigned)gx0 < 256u);
        bool in1 = rin && ((unsigned)(gx0 + 1) < 256u);
        int o = row * SS + pc0;
        lxs[0][o]     = in0 ? c1[0] + B1 : 0.f;
        lxs[0][o + 1] = in1 ? c1[1] + B1 : 0.f;
        lxs[1][o]     = in0 ? c3[0] + B3 : 0.f;
        lxs[1][o + 1] = in1 ? c3[1] + B3 : 0.f;
        lxs[2][o]     = in0 ? c5[0] + B5 : 0.f;
        lxs[2][o + 1] = in1 ? c5[1] + B5 : 0.f;
        lxs[3][o]     = in0 ? c7[0] + B7 : 0.f;
        lxs[3][o + 1] = in1 ? c7[1] + B7 : 0.f;
    }
    __syncthreads();

    // ---- per-pixel machinery: one horizontal pixel PAIR per thread ----
    const int ty  = tid >> 4;           // 0..31
    const int tx2 = (tid & 15) * 2;     // 0,2,...,30
    const int gy  = ty0 + ty, gx = tx0 + tx2;
    const int corner = ty * SS + tx2;   // lxs coords of (gy-7, gx-7)

    h2 brh[4];
#pragma unroll
    for (int i = 0; i < 4; i++) {
        const int s = 1 + 2 * i;        // 1,3,5,7
        const float* xs = lxs[i];
        // all offsets even (7±s even, (7±s)*47 even, 7*47+7=336 even) -> 8B aligned
        v2f ctr = *(const v2f*)&xs[corner + 7 * SS + 7];
        v2f n0  = *(const v2f*)&xs[corner + (7 - s) * SS + (7 - s)];
        v2f n1  = *(const v2f*)&xs[corner + (7 - s) * SS + 7];
        v2f n2  = *(const v2f*)&xs[corner + (7 - s) * SS + (7 + s)];
        v2f n3  = *(const v2f*)&xs[corner + 7 * SS + (7 + s)];
        v2f n4  = *(const v2f*)&xs[corner + (7 + s) * SS + (7 + s)];
        v2f n5  = *(const v2f*)&xs[corner + (7 + s) * SS + 7];
        v2f n6  = *(const v2f*)&xs[corner + (7 + s) * SS + (7 - s)];
        v2f n7  = *(const v2f*)&xs[corner + 7 * SS + (7 - s)];

        v2f T[8];
        T[0] = ctr - n0; T[1] = ctr - n1; T[2] = ctr - n2; T[3] = ctr - n3;
        T[4] = ctr - n4; T[5] = ctr - n5; T[6] = ctr - n6; T[7] = ctr - n7;
        v2f S[4];
#pragma unroll
        for (int k = 0; k < 4; k++) S[k] = T[k] + T[k + 4];

        const float w10   = l1w[i * 64 + c * 4 + 0];
        const float w11   = l1w[i * 64 + c * 4 + 1];
        const float w12   = l1w[i * 64 + c * 4 + 2];
        const float w13x2 = 2.f * l1w[i * 64 + c * 4 + 3];
        const float bb1   = l1b[i * 16 + c];

        v2f R[4];
#pragma unroll
        for (int m = 0; m < 4; m++) {
            v2f r = S[(m + 2) & 3] * w12 + bb1;
            r = S[(m + 3) & 3] * w11 + r;
            r = S[(m + 1) & 3] * w10 + r;
            R[m] = r;
        }

        h2 h8[8];
#pragma unroll
        for (int k = 0; k < 8; k++) {
            v2f o = (T[(k + 4) & 7] * w13x2 + R[k & 3]) * T[k];
            h8[k] = __builtin_convertvector(o, h2);
        }
        sort8_h2(h8);

        // l2 dot fully in packed fp16
        _Float16 l2bh = (_Float16)l2b[i * 16 + c];
        h2 acc = {l2bh, l2bh};
#pragma unroll
        for (int k = 0; k < 8; k++) {
            _Float16 wh = (_Float16)l2w[i * 128 + c * 8 + k];
            h2 wv = {wh, wh};
            acc = h8[k] * wv + acc;
        }
        brh[i] = acc;
    }

    // sort over branches + base_w dot, packed fp16
    sort4_h2(brh);
    h2 yvh = {(_Float16)0.f, (_Float16)0.f};
#pragma unroll
    for (int i = 0; i < 4; i++) {
        _Float16 bwh = (_Float16)bw[c * 4 + i];
        h2 bv = {bwh, bwh};
        yvh = brh[i] * bv + yvh;
    }
    const float bsc = bns[c], bbi = bnb[c];
    float zx = fmaf((float)yvh.x, bsc, bbi);
    float zy = fmaf((float)yvh.y, bsc, bbi);
    float sx = zx / (1.f + __expf(-zx));
    float sy = zy / (1.f + __expf(-zy));
    *(__half2*)&y16[(long)plane * HW + gy * 256 + gx] = __floats2half2_rn(sx, sy);
}

// ---------------- K3: final 1x1 16 -> 1 + sigmoid ----------------
__global__ __launch_bounds__(256) void k_final(const __half* __restrict__ y16,
                                               const float* __restrict__ fw,
                                               const float* __restrict__ fb,
                                               float* __restrict__ out) {
    long t  = (long)blockIdx.x * 256 + threadIdx.x;   // pair index
    long p0 = t * 2;
    int  b  = (int)(p0 >> 16);
    int  hw = (int)(p0 & 65535);

    float accx = fb[0], accy = fb[0];
#pragma unroll
    for (int cc = 0; cc < 16; cc++) {
        __half2 h = *(const __half2*)(y16 + (long)(b * 16 + cc) * HW + hw);
        float2 v = __half22float2(h);
        float wv = fw[cc];
        accx = fmaf(v.x, wv, accx);
        accy = fmaf(v.y, wv, accy);
    }
    float2 r;
    r.x = 1.f / (1.f + __expf(-accx));
    r.y = 1.f / (1.f + __expf(-accy));
    *(float2*)(out + p0) = r;
}

extern "C" void kernel_launch(void* const* d_in, const int* in_sizes, int n_in,
                              void* d_out, int out_size, void* d_ws, size_t ws_size,
                              hipStream_t stream) {
    (void)in_sizes; (void)n_in; (void)out_size; (void)ws_size;
    const float* cen   = (const float*)d_in[0];
    // d_in[1] = mas (unused by the reference)
    const float* in_w  = (const float*)d_in[2];
    const float* in_b  = (const float*)d_in[3];
    const float* dw_w1 = (const float*)d_in[4];
    const float* dw_b1 = (const float*)d_in[5];
    const float* dw_w3 = (const float*)d_in[6];
    const float* dw_b3 = (const float*)d_in[7];
    const float* dw_w5 = (const float*)d_in[8];
    const float* dw_b5 = (const float*)d_in[9];
    const float* dw_w7 = (const float*)d_in[10];
    const float* dw_b7 = (const float*)d_in[11];
    const float* l1w   = (const float*)d_in[12];
    const float* l1b   = (const float*)d_in[13];
    const float* l2w   = (const float*)d_in[14];
    const float* l2b   = (const float*)d_in[15];
    const float* bw    = (const float*)d_in[16];
    const float* bns   = (const float*)d_in[17];
    const float* bnb   = (const float*)d_in[18];
    const float* fw    = (const float*)d_in[19];
    const float* fb    = (const float*)d_in[20];

    float*  xbuf = (float*)d_ws;                           // (8,16,256,256) fp32, 33.5 MB
    __half* y16  = (__half*)(xbuf + (size_t)8 * 16 * HW);  // (8,16,256,256) fp16, 16.8 MB
    float*  out  = (float*)d_out;

    k_inconv<<<1024, 256, 0, stream>>>(cen, in_w, in_b, xbuf);
    k_main<<<dim3(64, 128), 512, 0, stream>>>(xbuf, dw_w1, dw_b1, dw_w3, dw_b3,
                                              dw_w5, dw_b5, dw_w7, dw_b7,
                                              l1w, l1b, l2w, l2b, bw, bns, bnb, y16);
    k_final<<<1024, 256, 0, stream>>>(y16, fw, fb, out);
}